// Round 8
// baseline (328.613 us; speedup 1.0000x reference)
//
#include <hip/hip_runtime.h>
#include <hip/hip_bf16.h>
#include <hip/hip_cooperative_groups.h>

namespace cg = cooperative_groups;

typedef short short8 __attribute__((ext_vector_type(8)));
typedef float float4_ __attribute__((ext_vector_type(4)));
typedef unsigned short ushort_t;

// params layout: theta[0:48], beta[48:58], c_r[58:67], c_o[67:69], c_s[69]
// outputs: J2d (32*128*21*2 = 172032), theta (196608), beta (40960)
#define OUT_THETA 172032
#define OUT_BETA  368640
#define NROW 4096
#define KDIM 5376
#define NPAD 80
#define KS 14            // split-K: 14 slices of 384 floats (3 x BK128)
#define BK 128
#define NBLK 448         // 2 tiles/block; worst-case co-residency 2/CU => 512 >= 448

// per-wave decode LDS layout (floats, within 912-float stride)
#define DP_P    0
#define DP_HP   70
#define DP_R    118      // 16x9
#define DP_JL   262
#define DP_RES  310      // 16x16
#define DP_AL   566      // 16x16
#define DP_CH   822      // 5x4
#define DP_M3   842      // 21x3
#define DP_STRIDE 912

__device__ __constant__ int c_jslot[16] = {0,5,6,7,9,10,11,17,18,19,13,14,15,1,2,3};
__device__ __constant__ int c_vslot[5]  = {4,8,12,16,20};

__device__ inline short f2bf(float f) {
  union { float f; unsigned u; } v; v.f = f;
  unsigned r = v.u + 0x7fffu + ((v.u >> 16) & 1u);
  return (short)(r >> 16);
}

__device__ inline short8 cvt8(float4_ a, float4_ b) {
  short8 r;
  r[0]=f2bf(a[0]); r[1]=f2bf(a[1]); r[2]=f2bf(a[2]); r[3]=f2bf(a[3]);
  r[4]=f2bf(b[0]); r[5]=f2bf(b[1]); r[6]=f2bf(b[2]); r[7]=f2bf(b[3]);
  return r;
}

// decode one (b,t) item; D = per-wave LDS base; every wave in the block runs
// the identical static __syncthreads() sequence.
__device__ void decode_item(float* D, int row, int l, bool valid,
    const float* __restrict__ part, const float* __restrict__ bvec,
    const float* __restrict__ comps, const float* __restrict__ meanh,
    const float* __restrict__ jsd, const float* __restrict__ jt,
    const float* __restrict__ psel, const float* __restrict__ ssel,
    const float* __restrict__ tsel, const float* __restrict__ wsel,
    float* __restrict__ out)
{
  // stage A: reduce split-K partials + bias; emit theta/beta
  if (valid) {
    float v = bvec[l];
    #pragma unroll
    for (int k = 0; k < KS; ++k) v += part[((size_t)k*NROW + row)*NPAD + l];
    D[DP_P + l] = v;
    if (l < 48) out[OUT_THETA + (size_t)row*48 + l] = v;
    else if (l < 58) out[OUT_BETA + (size_t)row*10 + (l-48)] = v;
    if (l < 6) {
      int c2 = l + 64;
      float w = bvec[c2];
      #pragma unroll
      for (int k = 0; k < KS; ++k) w += part[((size_t)k*NROW + row)*NPAD + c2];
      D[DP_P + c2] = w;
    }
  } else {
    D[DP_P + l] = 0.f;
    if (l < 6) D[DP_P + 64 + l] = 0.f;
  }
  __syncthreads();

  // stage B: hand_posed = [theta[:3], theta[3:48] @ comps + mean]
  if (l < 45) {
    float s = meanh[l];
    for (int k = 0; k < 45; ++k) s += D[DP_P + 3 + k]*comps[k*45 + l];
    D[DP_HP + 3 + l] = s;
  } else if (l < 48) D[DP_HP + (l-45)] = D[DP_P + (l-45)];
  __syncthreads();

  // stage C: rodrigues for 16 joints; stage D: J = jt + jsd . beta
  if (l < 16) {
    float rx = D[DP_HP + 3*l], ry = D[DP_HP + 3*l+1], rz = D[DP_HP + 3*l+2];
    float th = sqrtf(rx*rx + ry*ry + rz*rz + 1e-8f);
    float inv = 1.0f/th;
    float nx = rx*inv, ny = ry*inv, nz = rz*inv;
    float cth = cosf(th), sth = sinf(th), mc = 1.0f - cth;
    float* R = D + DP_R + 9*l;
    R[0] = cth + mc*nx*nx;     R[1] = mc*nx*ny - sth*nz;  R[2] = mc*nx*nz + sth*ny;
    R[3] = mc*ny*nx + sth*nz;  R[4] = cth + mc*ny*ny;     R[5] = mc*ny*nz - sth*nx;
    R[6] = mc*nz*nx - sth*ny;  R[7] = mc*nz*ny + sth*nx;  R[8] = cth + mc*nz*nz;
  }
  if (l < 48) {
    float s = jt[l];
    #pragma unroll
    for (int k = 0; k < 10; ++k) s += jsd[l*10+k]*D[DP_P + 48 + k];
    D[DP_JL + l] = s;
  }
  __syncthreads();

  // stage E: kinematic chain
  if (l < 16) {
    int r = l >> 2, c = l & 3;
    D[DP_RES + l] = (r < 3) ? ((c < 3) ? D[DP_R + 3*r + c] : D[DP_JL + r])
                            : ((c == 3) ? 1.f : 0.f);
  }
  __syncthreads();
  constexpr int PARS[15] = {0,1,2,0,4,5,0,7,8,0,10,11,0,13,14};
  #pragma unroll
  for (int i = 0; i < 15; ++i) {
    const int p = PARS[i];
    if (l < 16) {
      int r = l >> 2, c = l & 3;
      float s = (c == 3) ? D[DP_RES + p*16 + 4*r + 3] : 0.f;
      #pragma unroll
      for (int k = 0; k < 3; ++k) {
        float opv = (c < 3) ? D[DP_R + (i+1)*9 + 3*k + c]
                            : (D[DP_JL + 3*(i+1) + k] - D[DP_JL + 3*p + k]);
        s += D[DP_RES + p*16 + 4*r + k]*opv;
      }
      D[DP_RES + (i+1)*16 + l] = s;
    }
    __syncthreads();
  }

  // stage F: A = results with col3 -= results[:, :3] . J
  {
    int j = l >> 2, r = l & 3;
    const float* RS = D + DP_RES + j*16 + 4*r;
    float corr = RS[0]*D[DP_JL+3*j] + RS[1]*D[DP_JL+3*j+1] + RS[2]*D[DP_JL+3*j+2];
    float* AL = D + DP_AL + j*16 + 4*r;
    AL[0] = RS[0]; AL[1] = RS[1]; AL[2] = RS[2]; AL[3] = RS[3] - corr;
  }
  // stage G: curr_hand at the 5 selected vertices (lanes 0..14)
  if (l < 15) {
    int vi = l/3, ci = l%3;
    float s = tsel[l];
    #pragma unroll
    for (int k = 0; k < 10; ++k) s += ssel[l*10+k]*D[DP_P + 48 + k];
    for (int j15 = 0; j15 < 15; ++j15) {
      #pragma unroll
      for (int e = 0; e < 9; ++e) s += psel[l*135 + j15*9 + e]*D[DP_R + (j15+1)*9 + e];
    }
    D[DP_CH + vi*4 + ci] = s;
  }
  __syncthreads();

  // stage H: assemble J3d_re = joints (results[...,:3,3]) + 5 skinned vertices
  if (l < 48) {
    int j = l/3, c = l%3;
    D[DP_M3 + c_jslot[j]*3 + c] = D[DP_RES + j*16 + 4*c + 3];
  } else if (l < 63) {
    int s0 = l - 48; int vi = s0/3, r = s0%3;
    float m = 0.f;
    #pragma unroll
    for (int j = 0; j < 16; ++j) {
      const float* AL = D + DP_AL + j*16 + 4*r;
      float tv = AL[0]*D[DP_CH+vi*4] + AL[1]*D[DP_CH+vi*4+1]
               + AL[2]*D[DP_CH+vi*4+2] + AL[3];
      m += wsel[vi*16+j]*tv;
    }
    D[DP_M3 + c_vslot[vi]*3 + r] = m;
  }
  __syncthreads();

  // stage I: J2d = c_s * (J3d_re @ c_r3)[:, :2] + c_o
  if (valid && l < 42) {
    int k = l >> 1, d = l & 1;
    float s = D[DP_M3+k*3]*D[DP_P+58+d] + D[DP_M3+k*3+1]*D[DP_P+58+3+d]
            + D[DP_M3+k*3+2]*D[DP_P+58+6+d];
    out[((size_t)row*21 + k)*2 + d] = D[DP_P+69]*s + D[DP_P+67+d];
  }
  __syncthreads();   // LDS reuse safety before next item
}

// ================= single fused cooperative kernel =================
__global__ __launch_bounds__(256, 2) void fused_kernel(
    const float* __restrict__ x, const float* __restrict__ W,
    const float* __restrict__ bvec, const float* __restrict__ comps,
    const float* __restrict__ meanh, const float* __restrict__ tmpl,
    const float* __restrict__ shapedirs, const float* __restrict__ posedirs,
    const float* __restrict__ Jreg, const float* __restrict__ lbs,
    ushort_t* __restrict__ wfrag, float* __restrict__ jsd, float* __restrict__ jt,
    float* __restrict__ psel, float* __restrict__ ssel, float* __restrict__ tsel,
    float* __restrict__ wsel, float* __restrict__ part, float* __restrict__ out)
{
  __shared__ float LB[8192];                  // 32 KB: gemm A-tile / decode scratch
  cg::grid_group grid = cg::this_grid();
  int t = threadIdx.x;
  int gid = blockIdx.x*256 + t;               // 0..114687
  int gw = gid >> 6;                          // 0..1791
  int l = t & 63, w = t >> 6;

  // ---------------- phase 1: setup ----------------
  if (gw < 840) {
    // wfrag repack: item = gid in [0, 53760) = 80 n x 672 kgroups
    int n = gid / 672, kg = gid % 672;
    short8 o;
    if (n < 70) {
      const float* wp = W + (size_t)n*KDIM + kg*8;
      float4_ w0 = *(const float4_*)wp;
      float4_ w1 = *(const float4_*)(wp+4);
      o = cvt8(w0, w1);
    } else {
      o = (short8){0,0,0,0,0,0,0,0};
    }
    *(short8*)(wfrag + ((size_t)kg*NPAD + n)*8) = o;
  } else if (gw < 1368) {
    // jsd[j][c][k] / jt[j][c] wave reductions, wv in [0,528)
    int wv = gw - 840;
    float p = 0.f;
    if (wv < 480) {
      int j = wv/30, r = wv%30, c = r/10, kk = r%10;
      for (int v = l; v < 778; v += 64) p += Jreg[j*778+v]*shapedirs[(v*3+c)*10+kk];
    } else {
      int o = wv-480; int j = o/3, c = o%3;
      for (int v = l; v < 778; v += 64) p += Jreg[j*778+v]*tmpl[v*3+c];
    }
    for (int off = 32; off > 0; off >>= 1) p += __shfl_down(p, off);
    if (l == 0) { if (wv < 480) jsd[wv] = p; else jt[wv-480] = p; }
  } else if (gid >= 87552 && gid < 87552 + 2270) {
    const int vtx[5] = {743,333,443,555,678};
    int s = gid - 87552;
    if (s < 2025) { int vi = s/405, r = s%405, c = r/135, kk = r%135;
      psel[s] = posedirs[((size_t)vtx[vi]*3 + c)*135 + kk]; }
    else if (s < 2175) { int u = s-2025; int vi = u/30, r = u%30, c = r/10, kk = r%10;
      ssel[u] = shapedirs[((size_t)vtx[vi]*3 + c)*10 + kk]; }
    else if (s < 2190) { int u = s-2175; int vi = u/3, c = u%3;
      tsel[u] = tmpl[vtx[vi]*3 + c]; }
    else { int u = s-2190; int vi = u/16, j = u%16;
      wsel[u] = lbs[vtx[vi]*16 + j]; }
  }

  grid.sync();

  // ---------------- phase 2: GEMM, 2 tiles per block (same rows, kq and kq+7) ----------------
  {
    float* As = LB;
    int rb = blockIdx.x & 63;                 // 448 = 7 x 64
    int m_base = rb << 6;
    int q = l >> 4, lm = l & 15;
    int r = w*16 + lm;
    int sw = r & 7;
    const float4_* As4 = (const float4_*)As;

    #pragma unroll
    for (int half = 0; half < 2; ++half) {
      int kq = (blockIdx.x >> 6) + half*7;    // 0..6 then 7..13
      int k0 = kq * (3*BK);                   // kq*384

      float4_ acc0 = {0.f,0.f,0.f,0.f}, acc1 = acc0, acc2 = acc0, acc3 = acc0, acc4 = acc0;

      #pragma unroll
      for (int it = 0; it < 3; ++it) {
        #pragma unroll
        for (int j = 0; j < 8; ++j) {
          int f = j*256 + t;
          int row = f >> 5, p = f & 31;
          int g = p ^ (row & 7);
          const float* src = x + (size_t)(m_base + row)*KDIM + k0 + it*BK + g*4;
          __builtin_amdgcn_global_load_lds(
              (const __attribute__((address_space(1))) void*)src,
              (__attribute__((address_space(3))) void*)&As[(size_t)f*4], 16, 0, 0);
        }
        __syncthreads();

        #pragma unroll
        for (int c = 0; c < 4; ++c) {
          int cc = it*4 + c;
          int Lg = c*8 + q*2;
          float4_ f0 = As4[r*32 + (Lg ^ sw)];
          float4_ f1 = As4[r*32 + ((Lg+1) ^ sw)];
          const ushort_t* bp = wfrag + ((size_t)((k0>>3) + cc*4 + q)*NPAD + lm)*8;
          short8 b0 = *(const short8*)(bp);
          short8 b1 = *(const short8*)(bp+128);
          short8 b2 = *(const short8*)(bp+256);
          short8 b3 = *(const short8*)(bp+384);
          short8 b4 = *(const short8*)(bp+512);
          short8 af = cvt8(f0, f1);
          acc0 = __builtin_amdgcn_mfma_f32_16x16x32_bf16(af, b0, acc0, 0, 0, 0);
          acc1 = __builtin_amdgcn_mfma_f32_16x16x32_bf16(af, b1, acc1, 0, 0, 0);
          acc2 = __builtin_amdgcn_mfma_f32_16x16x32_bf16(af, b2, acc2, 0, 0, 0);
          acc3 = __builtin_amdgcn_mfma_f32_16x16x32_bf16(af, b3, acc3, 0, 0, 0);
          acc4 = __builtin_amdgcn_mfma_f32_16x16x32_bf16(af, b4, acc4, 0, 0, 0);
        }
        __syncthreads();
      }

      // C layout: row=(lane>>4)*4+rr, col=lane&15
      float* op = part + ((size_t)kq*NROW + m_base + w*16 + q*4)*NPAD + lm;
      #pragma unroll
      for (int rr = 0; rr < 4; ++rr) {
        op[(size_t)rr*NPAD +  0] = acc0[rr];
        op[(size_t)rr*NPAD + 16] = acc1[rr];
        op[(size_t)rr*NPAD + 32] = acc2[rr];
        op[(size_t)rr*NPAD + 48] = acc3[rr];
        op[(size_t)rr*NPAD + 64] = acc4[rr];
      }
    }
  }

  grid.sync();

  // ---------------- phase 3: decode, 4 waves/block, 3 masked passes ----------------
  {
    float* D = LB + w*DP_STRIDE;
    int wg = blockIdx.x*4 + w;                // 0..1791
    #pragma unroll
    for (int pass = 0; pass < 3; ++pass) {
      int row = wg + pass*1792;
      decode_item(D, row, l, row < NROW,
                  part, bvec, comps, meanh, jsd, jt, psel, ssel, tsel, wsel, out);
    }
  }
}

extern "C" void kernel_launch(void* const* d_in, const int* in_sizes, int n_in,
                              void* d_out, int out_size, void* d_ws, size_t ws_size,
                              hipStream_t stream) {
  const float* x         = (const float*)d_in[0];
  const float* W         = (const float*)d_in[1];
  const float* bvec      = (const float*)d_in[2];
  const float* comps     = (const float*)d_in[3];
  const float* meanh     = (const float*)d_in[4];
  const float* tmpl      = (const float*)d_in[5];
  const float* shapedirs = (const float*)d_in[6];
  const float* posedirs  = (const float*)d_in[7];
  const float* Jreg      = (const float*)d_in[8];
  const float* lbs       = (const float*)d_in[9];

  // ws layout: part (14*4096*80*4 = 18.3 MB) | wfrag 860160 | jsd 1920 | jt 192 |
  //            psel 8100 | ssel 600 | tsel 60 | wsel 320
  const size_t PART_ONE = (size_t)NROW*NPAD*4;

  char* ws = (char*)d_ws;
  float*    part  = (float*)ws;
  ushort_t* wfrag = (ushort_t*)(ws + (size_t)KS*PART_ONE);
  char*     tb    = ws + (size_t)KS*PART_ONE + 860160;
  float* jsd  = (float*)tb;
  float* jt   = (float*)(tb + 1920);
  float* psel = (float*)(tb + 1920 + 192);
  float* ssel = (float*)(tb + 1920 + 192 + 8100);
  float* tsel = (float*)(tb + 1920 + 192 + 8100 + 600);
  float* wsel = (float*)(tb + 1920 + 192 + 8100 + 600 + 60);
  float* out  = (float*)d_out;

  void* args[] = { &x, &W, &bvec, &comps, &meanh, &tmpl, &shapedirs, &posedirs,
                   &Jreg, &lbs, &wfrag, &jsd, &jt, &psel, &ssel, &tsel, &wsel,
                   &part, &out };
  hipLaunchCooperativeKernel((const void*)fused_kernel, dim3(NBLK), dim3(256),
                             args, 0, stream);
}